// Round 7
// baseline (430.206 us; speedup 1.0000x reference)
//
#include <hip/hip_runtime.h>
#include <math.h>

// Problem constants
#define BB   64
#define FC   24
#define NN   1000
#define HID  64
#define EMBD 32
#define TT   48
#define FF   8
#define INSZ 33

// Decoder tiling
#define CPB  32     // cells per block (M)
#define TPB  256    // 4 waves
#define MT   2      // m-tiles of 16
// Abuf columns: [0,64) H (bf16) | [64,96) E_hi | [96,128) E_lo | pad
#define AST  136    // stride in bf16 elems; 136*2=272 B, 16B-aligned rows

typedef __attribute__((ext_vector_type(8))) short bf16x8;
typedef __attribute__((ext_vector_type(4))) short bf16x4;
typedef __attribute__((ext_vector_type(4))) float f32x4;

static __device__ __forceinline__ unsigned short f2bf(float f) {
    unsigned u = __builtin_bit_cast(unsigned, f);
    u += 0x7FFFu + ((u >> 16) & 1u);      // RNE
    return (unsigned short)(u >> 16);
}
static __device__ __forceinline__ float bf2f(unsigned short h) {
    return __builtin_bit_cast(float, (unsigned)h << 16);
}
static __device__ __forceinline__ float fast_sigmoid(float v) {
    float e = __builtin_amdgcn_exp2f(-1.4426950408889634f * v);
    return __builtin_amdgcn_rcpf(1.0f + e);
}
static __device__ __forceinline__ float fast_tanh(float v) {
    float vv = fminf(fmaxf(v, -15.0f), 15.0f);
    float e = __builtin_amdgcn_exp2f(2.8853900817779268f * vv);
    return 1.0f - 2.0f * __builtin_amdgcn_rcpf(e + 1.0f);
}

__global__ __launch_bounds__(TPB) __attribute__((amdgpu_waves_per_eu(4)))
void gru_decoder(
    const float* __restrict__ X,    // [B][TT][N][F]
    const float* __restrict__ hn0,  // [B*N][HID]
    const float* __restrict__ xn,   // [B][N][1]
    const float* __restrict__ emb,  // [NEMB][EMBD]
    const float* __restrict__ Wih,  // [3*HID][INSZ]
    const float* __restrict__ Whh,  // [3*HID][HID]
    const float* __restrict__ bih,  // [3*HID]
    const float* __restrict__ bhh,  // [3*HID]
    const float* __restrict__ Wout, // [1][HID]
    const float* __restrict__ bout, // [1]
    float* __restrict__ out)        // [B][FC][N][1]
{
    __shared__ __align__(16) unsigned short Abuf[CPB * AST]; // 8704 B
    __shared__ int   idxbuf[FC * CPB];                       // 3072 B
    __shared__ float xbuf[CPB];

    const int tid  = threadIdx.x;
    const int lane = tid & 63;
    const int g    = tid >> 6;         // wave 0..3 owns gate-cols g*16..g*16+15
    const int quad = lane >> 4;
    const int l15  = lane & 15;
    const int jcol = g * 16 + l15;
    const int rowb = quad * 4;
    const int cell0 = blockIdx.x * CPB;

    // ---- stage idx for all FC steps ----
    for (int e = tid; e < FC * CPB; e += TPB) {
        int t = e >> 5, m = e & 31;
        int cell = cell0 + m;
        int b = cell / NN, n = cell - b * NN;
        idxbuf[t * CPB + m] = (int)X[(((size_t)b * TT + t) * NN + n) * FF + 7];
    }
    if (tid < CPB) xbuf[tid] = xn[cell0 + tid];
    __syncthreads();   // idxbuf needed by E-staging below

    // ---- persistent B fragments: Whh^T (24 VGPRs) ----
    bf16x8 Bf[3][2];
    #pragma unroll
    for (int gate = 0; gate < 3; ++gate) {
        #pragma unroll
        for (int ks = 0; ks < 2; ++ks) {
            const float* src = Whh + (size_t)(gate * HID + jcol) * HID + ks * 32 + quad * 8;
            float4 lo = *(const float4*)src;
            float4 hi = *(const float4*)(src + 4);
            bf16x8 f;
            f[0] = (short)f2bf(lo.x); f[1] = (short)f2bf(lo.y);
            f[2] = (short)f2bf(lo.z); f[3] = (short)f2bf(lo.w);
            f[4] = (short)f2bf(hi.x); f[5] = (short)f2bf(hi.y);
            f[6] = (short)f2bf(hi.z); f[7] = (short)f2bf(hi.w);
            Bf[gate][ks] = f;
        }
    }
    // ---- persistent B fragments: Wih emb-columns, hi + lo split (24 VGPRs) ----
    bf16x8 Bf2h[3], Bf2l[3];
    #pragma unroll
    for (int gate = 0; gate < 3; ++gate) {
        const float* src = Wih + (size_t)(gate * HID + jcol) * INSZ + 1 + quad * 8;
        bf16x8 fh, fl;
        #pragma unroll
        for (int e2 = 0; e2 < 8; ++e2) {
            float w = src[e2];
            unsigned short h = f2bf(w);
            fh[e2] = (short)h;
            fl[e2] = (short)f2bf(w - bf2f(h));
        }
        Bf2h[gate] = fh;
        Bf2l[gate] = fl;
    }

    const float w0r = Wih[(size_t)jcol * INSZ];
    const float w0z = Wih[(size_t)(HID + jcol) * INSZ];
    const float w0n = Wih[(size_t)(2 * HID + jcol) * INSZ];
    const float br  = bih[jcol] + bhh[jcol];
    const float bz  = bih[HID + jcol] + bhh[HID + jcol];
    const float bn  = bih[2 * HID + jcol];
    const float bhn = bhh[2 * HID + jcol];
    const float bout0 = bout[0];

    // ---- out-dot role: 8 consecutive lanes per cell ----
    const int kslice = lane & 7;           // k-slice 0..7 (8 k's each)
    const int cd_m   = g * 8 + (lane >> 3);
    float wout_r[8];
    #pragma unroll
    for (int e2 = 0; e2 < 8; ++e2) wout_r[e2] = Wout[kslice * 8 + e2];
    const int cd_cell = cell0 + cd_m;
    const int cd_b = cd_cell / NN, cd_n = cd_cell - cd_b * NN;
    const size_t obase = (size_t)cd_b * FC * NN + cd_n;

    // ---- h0: fp32 regs + bf16 Abuf H-region ----
    float hold[MT][4];
    #pragma unroll
    for (int mt = 0; mt < MT; ++mt) {
        #pragma unroll
        for (int rr = 0; rr < 4; ++rr) {
            int m = mt * 16 + rowb + rr;
            float h = hn0[((size_t)cell0 + m) * HID + jcol];
            hold[mt][rr] = h;
            Abuf[m * AST + jcol] = f2bf(h);
        }
    }
    // ---- E-staging for t=0 (hi+lo split) ----
    {
        const int c = tid >> 3, kg = tid & 7;
        int idx = idxbuf[c];
        float4 v = *(const float4*)(emb + (size_t)idx * EMBD + kg * 4);
        bf16x4 wh, wl;
        float vv[4] = {v.x, v.y, v.z, v.w};
        #pragma unroll
        for (int q = 0; q < 4; ++q) {
            unsigned short h = f2bf(vv[q]);
            wh[q] = (short)h;
            wl[q] = (short)f2bf(vv[q] - bf2f(h));
        }
        *(bf16x4*)&Abuf[c * AST + HID + kg * 4]      = wh;
        *(bf16x4*)&Abuf[c * AST + HID + 32 + kg * 4] = wl;
    }
    __syncthreads();

    for (int t = 0; t < FC; ++t) {
        // ---- phase A: matrix pipe. n-gate keeps H-path and E-path in
        //      SEPARATE accumulators: only the H-path is scaled by r. ----
        f32x4 accr[MT], accz[MT], acch[MT], acce[MT];
        #pragma unroll
        for (int mt = 0; mt < MT; ++mt) {
            const int rb = (mt * 16 + l15) * AST;
            const bf16x8 a0  = *(const bf16x8*)&Abuf[rb + quad * 8];
            const bf16x8 a1  = *(const bf16x8*)&Abuf[rb + 32 + quad * 8];
            const bf16x8 a2h = *(const bf16x8*)&Abuf[rb + HID + quad * 8];
            const bf16x8 a2l = *(const bf16x8*)&Abuf[rb + HID + 32 + quad * 8];
            f32x4 z4 = {0.f, 0.f, 0.f, 0.f};
            // r-gate: H + E (all summed before sigmoid)
            accr[mt] = __builtin_amdgcn_mfma_f32_16x16x32_bf16(a0,  Bf[0][0], z4, 0, 0, 0);
            accr[mt] = __builtin_amdgcn_mfma_f32_16x16x32_bf16(a1,  Bf[0][1], accr[mt], 0, 0, 0);
            accr[mt] = __builtin_amdgcn_mfma_f32_16x16x32_bf16(a2h, Bf2h[0],  accr[mt], 0, 0, 0);
            accr[mt] = __builtin_amdgcn_mfma_f32_16x16x32_bf16(a2l, Bf2h[0],  accr[mt], 0, 0, 0);
            accr[mt] = __builtin_amdgcn_mfma_f32_16x16x32_bf16(a2h, Bf2l[0],  accr[mt], 0, 0, 0);
            // z-gate: H + E
            accz[mt] = __builtin_amdgcn_mfma_f32_16x16x32_bf16(a0,  Bf[1][0], z4, 0, 0, 0);
            accz[mt] = __builtin_amdgcn_mfma_f32_16x16x32_bf16(a1,  Bf[1][1], accz[mt], 0, 0, 0);
            accz[mt] = __builtin_amdgcn_mfma_f32_16x16x32_bf16(a2h, Bf2h[1],  accz[mt], 0, 0, 0);
            accz[mt] = __builtin_amdgcn_mfma_f32_16x16x32_bf16(a2l, Bf2h[1],  accz[mt], 0, 0, 0);
            accz[mt] = __builtin_amdgcn_mfma_f32_16x16x32_bf16(a2h, Bf2l[1],  accz[mt], 0, 0, 0);
            // n-gate hidden path (inside r·(...))
            acch[mt] = __builtin_amdgcn_mfma_f32_16x16x32_bf16(a0,  Bf[2][0], z4, 0, 0, 0);
            acch[mt] = __builtin_amdgcn_mfma_f32_16x16x32_bf16(a1,  Bf[2][1], acch[mt], 0, 0, 0);
            // n-gate input path (OUTSIDE r)
            acce[mt] = __builtin_amdgcn_mfma_f32_16x16x32_bf16(a2h, Bf2h[2],  z4, 0, 0, 0);
            acce[mt] = __builtin_amdgcn_mfma_f32_16x16x32_bf16(a2l, Bf2h[2],  acce[mt], 0, 0, 0);
            acce[mt] = __builtin_amdgcn_mfma_f32_16x16x32_bf16(a2h, Bf2l[2],  acce[mt], 0, 0, 0);
        }

        // ---- overlapped: out-dot for step t-1 (reads Abuf H-region) ----
        if (t > 0) {
            bf16x8 hv = *(const bf16x8*)&Abuf[cd_m * AST + kslice * 8];
            const unsigned* hv32 = (const unsigned*)&hv;
            float o = 0.f;
            #pragma unroll
            for (int q = 0; q < 4; ++q) {
                unsigned v = hv32[q];
                o = fmaf(wout_r[2 * q],     __builtin_bit_cast(float, v << 16),         o);
                o = fmaf(wout_r[2 * q + 1], __builtin_bit_cast(float, v & 0xFFFF0000u), o);
            }
            o += __shfl_xor(o, 1);
            o += __shfl_xor(o, 2);
            o += __shfl_xor(o, 4);
            if ((lane & 7) == 0) {
                float oo = o + bout0;
                out[obase + (size_t)(t - 1) * NN] = oo;
                xbuf[cd_m] = oo;
            }
        }
        __syncthreads();   // xbuf ready; Abuf reads drained before writes

        // ---- phase B: gates + h update (no global loads) ----
        #pragma unroll
        for (int mt = 0; mt < MT; ++mt) {
            #pragma unroll
            for (int rr = 0; rr < 4; ++rr) {
                int m   = mt * 16 + rowb + rr;
                float xp = xbuf[m];
                float ar = fmaf(w0r, xp, br);
                float az = fmaf(w0z, xp, bz);
                float an = fmaf(w0n, xp, bn) + acce[mt][rr];
                float r  = fast_sigmoid(ar + accr[mt][rr]);
                float z  = fast_sigmoid(az + accz[mt][rr]);
                float nv = fast_tanh(an + r * (acch[mt][rr] + bhn));
                float hnew = nv + z * (hold[mt][rr] - nv);
                hold[mt][rr] = hnew;
                Abuf[m * AST + jcol] = f2bf(hnew);
            }
        }
        // ---- E-staging for step t+1 (E-region; disjoint from H writes) ----
        if (t + 1 < FC) {
            const int c = tid >> 3, kg = tid & 7;
            int idx = idxbuf[(t + 1) * CPB + c];
            float4 v = *(const float4*)(emb + (size_t)idx * EMBD + kg * 4);
            bf16x4 wh, wl;
            float vv[4] = {v.x, v.y, v.z, v.w};
            #pragma unroll
            for (int q = 0; q < 4; ++q) {
                unsigned short h = f2bf(vv[q]);
                wh[q] = (short)h;
                wl[q] = (short)f2bf(vv[q] - bf2f(h));
            }
            *(bf16x4*)&Abuf[c * AST + HID + kg * 4]      = wh;
            *(bf16x4*)&Abuf[c * AST + HID + 32 + kg * 4] = wl;
        }
        __syncthreads();   // h_new + E ready for next phase A
    }

    // ---- epilogue: out for final step ----
    {
        bf16x8 hv = *(const bf16x8*)&Abuf[cd_m * AST + kslice * 8];
        const unsigned* hv32 = (const unsigned*)&hv;
        float o = 0.f;
        #pragma unroll
        for (int q = 0; q < 4; ++q) {
            unsigned v = hv32[q];
            o = fmaf(wout_r[2 * q],     __builtin_bit_cast(float, v << 16),         o);
            o = fmaf(wout_r[2 * q + 1], __builtin_bit_cast(float, v & 0xFFFF0000u), o);
        }
        o += __shfl_xor(o, 1);
        o += __shfl_xor(o, 2);
        o += __shfl_xor(o, 4);
        if ((lane & 7) == 0) out[obase + (size_t)(FC - 1) * NN] = o + bout0;
    }
}

extern "C" void kernel_launch(void* const* d_in, const int* in_sizes, int n_in,
                              void* d_out, int out_size, void* d_ws, size_t ws_size,
                              hipStream_t stream) {
    (void)in_sizes; (void)n_in; (void)out_size; (void)d_ws; (void)ws_size;
    const float* X    = (const float*)d_in[0];
    const float* hn   = (const float*)d_in[1];
    const float* xn   = (const float*)d_in[2];
    const float* emb  = (const float*)d_in[3];
    const float* Wih  = (const float*)d_in[4];
    const float* Whh  = (const float*)d_in[5];
    const float* bih  = (const float*)d_in[6];
    const float* bhh  = (const float*)d_in[7];
    const float* Wout = (const float*)d_in[8];
    const float* bout = (const float*)d_in[9];
    float* out = (float*)d_out;

    const int blocks = (BB * NN) / CPB;   // 2000
    gru_decoder<<<blocks, TPB, 0, stream>>>(X, hn, xn, emb, Wih, Whh,
                                            bih, bhh, Wout, bout, out);
}

// Round 8
// 271.474 us; speedup vs baseline: 1.5847x; 1.5847x over previous
//
#include <hip/hip_runtime.h>
#include <math.h>

// Problem constants
#define BB   64
#define FC   24
#define NN   1000
#define HID  64
#define EMBD 32
#define TT   48
#define FF   8
#define INSZ 33

// Decoder tiling
#define CPB  32     // cells per block (M)
#define TPB  256    // 4 waves
#define MT   2      // m-tiles of 16
// Abuf columns: [0,64) H (bf16) | [64,96) E | pad
#define AST  104    // stride in bf16 elems; 104*2=208 B, 16B-aligned rows

typedef __attribute__((ext_vector_type(8))) short bf16x8;
typedef __attribute__((ext_vector_type(4))) short bf16x4;
typedef __attribute__((ext_vector_type(4))) float f32x4;

static __device__ __forceinline__ unsigned short f2bf(float f) {
    unsigned u = __builtin_bit_cast(unsigned, f);
    u += 0x7FFFu + ((u >> 16) & 1u);      // RNE
    return (unsigned short)(u >> 16);
}
static __device__ __forceinline__ float fast_sigmoid(float v) {
    float e = __builtin_amdgcn_exp2f(-1.4426950408889634f * v);
    return __builtin_amdgcn_rcpf(1.0f + e);
}
static __device__ __forceinline__ float fast_tanh(float v) {
    float vv = fminf(fmaxf(v, -15.0f), 15.0f);
    float e = __builtin_amdgcn_exp2f(2.8853900817779268f * vv);
    return 1.0f - 2.0f * __builtin_amdgcn_rcpf(e + 1.0f);
}

__global__ __launch_bounds__(TPB) __attribute__((amdgpu_waves_per_eu(2)))
void gru_decoder(
    const float* __restrict__ X,    // [B][TT][N][F]
    const float* __restrict__ hn0,  // [B*N][HID]
    const float* __restrict__ xn,   // [B][N][1]
    const float* __restrict__ emb,  // [NEMB][EMBD]
    const float* __restrict__ Wih,  // [3*HID][INSZ]
    const float* __restrict__ Whh,  // [3*HID][HID]
    const float* __restrict__ bih,  // [3*HID]
    const float* __restrict__ bhh,  // [3*HID]
    const float* __restrict__ Wout, // [1][HID]
    const float* __restrict__ bout, // [1]
    float* __restrict__ out)        // [B][FC][N][1]
{
    __shared__ __align__(16) unsigned short Abuf[CPB * AST]; // 6656 B
    __shared__ int   idxbuf[FC * CPB];                       // 3072 B
    __shared__ float xbuf[CPB];

    const int tid  = threadIdx.x;
    const int lane = tid & 63;
    const int g    = tid >> 6;         // wave 0..3 owns gate-cols g*16..g*16+15
    const int quad = lane >> 4;
    const int l15  = lane & 15;
    const int jcol = g * 16 + l15;
    const int rowb = quad * 4;
    const int cell0 = blockIdx.x * CPB;

    // ---- stage idx for all FC steps ----
    for (int e = tid; e < FC * CPB; e += TPB) {
        int t = e >> 5, m = e & 31;
        int cell = cell0 + m;
        int b = cell / NN, n = cell - b * NN;
        idxbuf[t * CPB + m] = (int)X[(((size_t)b * TT + t) * NN + n) * FF + 7];
    }
    if (tid < CPB) xbuf[tid] = xn[cell0 + tid];
    __syncthreads();   // idxbuf needed by E-staging below

    // ---- persistent B fragments: Whh^T (24 VGPRs) ----
    bf16x8 Bf[3][2];
    #pragma unroll
    for (int gate = 0; gate < 3; ++gate) {
        #pragma unroll
        for (int ks = 0; ks < 2; ++ks) {
            const float* src = Whh + (size_t)(gate * HID + jcol) * HID + ks * 32 + quad * 8;
            float4 lo = *(const float4*)src;
            float4 hi = *(const float4*)(src + 4);
            bf16x8 f;
            f[0] = (short)f2bf(lo.x); f[1] = (short)f2bf(lo.y);
            f[2] = (short)f2bf(lo.z); f[3] = (short)f2bf(lo.w);
            f[4] = (short)f2bf(hi.x); f[5] = (short)f2bf(hi.y);
            f[6] = (short)f2bf(hi.z); f[7] = (short)f2bf(hi.w);
            Bf[gate][ks] = f;
        }
    }
    // ---- persistent B fragments: Wih emb-columns (12 VGPRs) ----
    bf16x8 Bf2[3];
    #pragma unroll
    for (int gate = 0; gate < 3; ++gate) {
        const float* src = Wih + (size_t)(gate * HID + jcol) * INSZ + 1 + quad * 8;
        bf16x8 f;
        #pragma unroll
        for (int e2 = 0; e2 < 8; ++e2) f[e2] = (short)f2bf(src[e2]);
        Bf2[gate] = f;
    }

    const float w0r = Wih[(size_t)jcol * INSZ];
    const float w0z = Wih[(size_t)(HID + jcol) * INSZ];
    const float w0n = Wih[(size_t)(2 * HID + jcol) * INSZ];
    const float br  = bih[jcol] + bhh[jcol];
    const float bz  = bih[HID + jcol] + bhh[HID + jcol];
    const float bn  = bih[2 * HID + jcol];
    const float bhn = bhh[2 * HID + jcol];
    const float bout0 = bout[0];

    // ---- out-dot role: 8 consecutive lanes per cell ----
    const int kslice = lane & 7;           // k-slice 0..7 (8 k's each)
    const int cd_m   = g * 8 + (lane >> 3);
    float wout_r[8];
    #pragma unroll
    for (int e2 = 0; e2 < 8; ++e2) wout_r[e2] = Wout[kslice * 8 + e2];
    const int cd_cell = cell0 + cd_m;
    const int cd_b = cd_cell / NN, cd_n = cd_cell - cd_b * NN;
    const size_t obase = (size_t)cd_b * FC * NN + cd_n;

    // ---- h0: fp32 regs + bf16 Abuf H-region ----
    float hold[MT][4];
    #pragma unroll
    for (int mt = 0; mt < MT; ++mt) {
        #pragma unroll
        for (int rr = 0; rr < 4; ++rr) {
            int m = mt * 16 + rowb + rr;
            float h = hn0[((size_t)cell0 + m) * HID + jcol];
            hold[mt][rr] = h;
            Abuf[m * AST + jcol] = f2bf(h);
        }
    }
    // ---- E-staging for t=0 ----
    {
        const int c = tid >> 3, kg = tid & 7;
        int idx = idxbuf[c];
        float4 v = *(const float4*)(emb + (size_t)idx * EMBD + kg * 4);
        bf16x4 w;
        w[0] = (short)f2bf(v.x); w[1] = (short)f2bf(v.y);
        w[2] = (short)f2bf(v.z); w[3] = (short)f2bf(v.w);
        *(bf16x4*)&Abuf[c * AST + HID + kg * 4] = w;
    }
    __syncthreads();

    for (int t = 0; t < FC; ++t) {
        // ---- phase A: matrix pipe. n-gate keeps H-path and E-path in
        //      SEPARATE accumulators: only the H-path is scaled by r. ----
        f32x4 accr[MT], accz[MT], acch[MT], acce[MT];
        #pragma unroll
        for (int mt = 0; mt < MT; ++mt) {
            const int rb = (mt * 16 + l15) * AST;
            const bf16x8 a0 = *(const bf16x8*)&Abuf[rb + quad * 8];
            const bf16x8 a1 = *(const bf16x8*)&Abuf[rb + 32 + quad * 8];
            const bf16x8 a2 = *(const bf16x8*)&Abuf[rb + HID + quad * 8];
            f32x4 z4 = {0.f, 0.f, 0.f, 0.f};
            // r-gate: H + E (all summed before sigmoid)
            accr[mt] = __builtin_amdgcn_mfma_f32_16x16x32_bf16(a0, Bf[0][0], z4, 0, 0, 0);
            accr[mt] = __builtin_amdgcn_mfma_f32_16x16x32_bf16(a1, Bf[0][1], accr[mt], 0, 0, 0);
            accr[mt] = __builtin_amdgcn_mfma_f32_16x16x32_bf16(a2, Bf2[0],   accr[mt], 0, 0, 0);
            // z-gate: H + E
            accz[mt] = __builtin_amdgcn_mfma_f32_16x16x32_bf16(a0, Bf[1][0], z4, 0, 0, 0);
            accz[mt] = __builtin_amdgcn_mfma_f32_16x16x32_bf16(a1, Bf[1][1], accz[mt], 0, 0, 0);
            accz[mt] = __builtin_amdgcn_mfma_f32_16x16x32_bf16(a2, Bf2[1],   accz[mt], 0, 0, 0);
            // n-gate hidden path (inside r·(...))
            acch[mt] = __builtin_amdgcn_mfma_f32_16x16x32_bf16(a0, Bf[2][0], z4, 0, 0, 0);
            acch[mt] = __builtin_amdgcn_mfma_f32_16x16x32_bf16(a1, Bf[2][1], acch[mt], 0, 0, 0);
            // n-gate input path (OUTSIDE r)
            acce[mt] = __builtin_amdgcn_mfma_f32_16x16x32_bf16(a2, Bf2[2],   z4, 0, 0, 0);
        }

        // ---- overlapped: out-dot for step t-1 (reads Abuf H-region) ----
        if (t > 0) {
            bf16x8 hv = *(const bf16x8*)&Abuf[cd_m * AST + kslice * 8];
            const unsigned* hv32 = (const unsigned*)&hv;
            float o = 0.f;
            #pragma unroll
            for (int q = 0; q < 4; ++q) {
                unsigned v = hv32[q];
                o = fmaf(wout_r[2 * q],     __builtin_bit_cast(float, v << 16),         o);
                o = fmaf(wout_r[2 * q + 1], __builtin_bit_cast(float, v & 0xFFFF0000u), o);
            }
            o += __shfl_xor(o, 1);
            o += __shfl_xor(o, 2);
            o += __shfl_xor(o, 4);
            if ((lane & 7) == 0) {
                float oo = o + bout0;
                out[obase + (size_t)(t - 1) * NN] = oo;
                xbuf[cd_m] = oo;
            }
        }
        __syncthreads();   // xbuf ready; Abuf reads drained before writes

        // ---- phase B: gates + h update (no global loads) ----
        #pragma unroll
        for (int mt = 0; mt < MT; ++mt) {
            #pragma unroll
            for (int rr = 0; rr < 4; ++rr) {
                int m   = mt * 16 + rowb + rr;
                float xp = xbuf[m];
                float ar = fmaf(w0r, xp, br);
                float az = fmaf(w0z, xp, bz);
                float an = fmaf(w0n, xp, bn) + acce[mt][rr];
                float r  = fast_sigmoid(ar + accr[mt][rr]);
                float z  = fast_sigmoid(az + accz[mt][rr]);
                float nv = fast_tanh(an + r * (acch[mt][rr] + bhn));
                float hnew = nv + z * (hold[mt][rr] - nv);
                hold[mt][rr] = hnew;
                Abuf[m * AST + jcol] = f2bf(hnew);
            }
        }
        // ---- E-staging for step t+1 (E-region; disjoint from H writes) ----
        if (t + 1 < FC) {
            const int c = tid >> 3, kg = tid & 7;
            int idx = idxbuf[(t + 1) * CPB + c];
            float4 v = *(const float4*)(emb + (size_t)idx * EMBD + kg * 4);
            bf16x4 w;
            w[0] = (short)f2bf(v.x); w[1] = (short)f2bf(v.y);
            w[2] = (short)f2bf(v.z); w[3] = (short)f2bf(v.w);
            *(bf16x4*)&Abuf[c * AST + HID + kg * 4] = w;
        }
        __syncthreads();   // h_new + E ready for next phase A
    }

    // ---- epilogue: out for final step ----
    {
        bf16x8 hv = *(const bf16x8*)&Abuf[cd_m * AST + kslice * 8];
        const unsigned* hv32 = (const unsigned*)&hv;
        float o = 0.f;
        #pragma unroll
        for (int q = 0; q < 4; ++q) {
            unsigned v = hv32[q];
            o = fmaf(wout_r[2 * q],     __builtin_bit_cast(float, v << 16),         o);
            o = fmaf(wout_r[2 * q + 1], __builtin_bit_cast(float, v & 0xFFFF0000u), o);
        }
        o += __shfl_xor(o, 1);
        o += __shfl_xor(o, 2);
        o += __shfl_xor(o, 4);
        if ((lane & 7) == 0) out[obase + (size_t)(FC - 1) * NN] = o + bout0;
    }
}

extern "C" void kernel_launch(void* const* d_in, const int* in_sizes, int n_in,
                              void* d_out, int out_size, void* d_ws, size_t ws_size,
                              hipStream_t stream) {
    (void)in_sizes; (void)n_in; (void)out_size; (void)d_ws; (void)ws_size;
    const float* X    = (const float*)d_in[0];
    const float* hn   = (const float*)d_in[1];
    const float* xn   = (const float*)d_in[2];
    const float* emb  = (const float*)d_in[3];
    const float* Wih  = (const float*)d_in[4];
    const float* Whh  = (const float*)d_in[5];
    const float* bih  = (const float*)d_in[6];
    const float* bhh  = (const float*)d_in[7];
    const float* Wout = (const float*)d_in[8];
    const float* bout = (const float*)d_in[9];
    float* out = (float*)d_out;

    const int blocks = (BB * NN) / CPB;   // 2000
    gru_decoder<<<blocks, TPB, 0, stream>>>(X, hn, xn, emb, Wih, Whh,
                                            bih, bhh, Wout, bout, out);
}